// Round 6
// baseline (475.479 us; speedup 1.0000x reference)
//
#include <hip/hip_runtime.h>
#include <hip/hip_bf16.h>

// DPP helper: float lane-crossing via v_mov_b32_dpp (VALU, ~4cyc; no DS).
// bound_ctrl=true -> lanes with invalid source read 0.0f.
#define DPPF(x, ctrl) \
    __int_as_float(__builtin_amdgcn_mov_dpp(__float_as_int(x), (ctrl), 0xf, 0xf, true))

typedef float f32x4 __attribute__((ext_vector_type(4)));

// ---------------------------------------------------------------------------
// Kernel 1 (unchanged, verified): one WAVE per (b,t) row; 64 lanes x 16 = 1024.
// Emits gat[row][lane] = float4{ P(lab 2k), P(lab 2k+1), P(blank), 0 } —
// PROBABILITIES (softmax). Also zeroes out[0].
// ---------------------------------------------------------------------------
__global__ void lse_gather_kernel(const float* __restrict__ pred,
                                  const int* __restrict__ tgt,
                                  float4* __restrict__ gat,
                                  float* __restrict__ out,
                                  int T, int V, int L, int nrows) {
    if (blockIdx.x == 0 && threadIdx.x == 0) out[0] = 0.0f;

    const int wid = blockIdx.x * (blockDim.x >> 6) + (threadIdx.x >> 6);
    if (wid >= nrows) return;
    const int lane = threadIdx.x & 63;
    const int b = wid / T;

    const float* row = pred + (size_t)wid * V;   // wid == b*T + t
    float4 w0 = ((const float4*)row)[lane];
    float4 w1 = ((const float4*)row)[lane + 64];
    float4 w2 = ((const float4*)row)[lane + 128];
    float4 w3 = ((const float4*)row)[lane + 192];

    float m = fmaxf(fmaxf(fmaxf(w0.x, w0.y), fmaxf(w0.z, w0.w)),
                    fmaxf(fmaxf(w1.x, w1.y), fmaxf(w1.z, w1.w)));
    m = fmaxf(m, fmaxf(fmaxf(w2.x, w2.y), fmaxf(w2.z, w2.w)));
    m = fmaxf(m, fmaxf(fmaxf(w3.x, w3.y), fmaxf(w3.z, w3.w)));
    #pragma unroll
    for (int off = 1; off < 64; off <<= 1) m = fmaxf(m, __shfl_xor(m, off, 64));

    float s = __expf(w0.x - m) + __expf(w0.y - m) + __expf(w0.z - m) + __expf(w0.w - m)
            + __expf(w1.x - m) + __expf(w1.y - m) + __expf(w1.z - m) + __expf(w1.w - m)
            + __expf(w2.x - m) + __expf(w2.y - m) + __expf(w2.z - m) + __expf(w2.w - m)
            + __expf(w3.x - m) + __expf(w3.y - m) + __expf(w3.z - m) + __expf(w3.w - m);
    #pragma unroll
    for (int off = 1; off < 64; off <<= 1) s += __shfl_xor(s, off, 64);

    const float lse = m + __logf(s);

    float pz = __expf(row[0] - lse);        // blank probability
    float px = 0.0f, py = 0.0f;             // 0 = additive identity: masks
    const int l0 = 2 * lane, l1i = 2 * lane + 1;
    if (l0  < L) px = __expf(row[tgt[b * L + l0 ]] - lse);  // row is L1-hot
    if (l1i < L) py = __expf(row[tgt[b * L + l1i]] - lse);

    float4 o; o.x = px; o.y = py; o.z = pz; o.w = 0.0f;
    gat[(size_t)wid * 64 + lane] = o;
}

// ---------------------------------------------------------------------------
// Kernel 2: CTC alpha, ONE WAVE per batch element, LINEAR (prob) domain.
// EXACT round-4 verified math. ONE mechanism change: the 24-deep prefetch
// ring loads go through a VOLATILE pointer. Volatile loads keep their issue
// order (cannot be sunk to uses or eliminated), so 24 stay physically in
// flight; the compiler's SIInsertWaitcnts scoreboard then emits precise
// counted s_waitcnt vmcnt(N) before each use — the T4 pattern, but with
// machine-verified accounting (handles spills/compiled loads), unlike the
// round-5 hand-asm that faulted. No inline asm anywhere.
// Diagnostic: VGPR_Count 44 -> >=120 iff the ring materialized.
// ---------------------------------------------------------------------------
__global__ __launch_bounds__(64, 1)
void ctc_alpha_wave(const float4* __restrict__ gat,
                    const int* __restrict__ tgt,
                    const int* __restrict__ in_len,
                    const int* __restrict__ tg_len,
                    float* __restrict__ out,
                    int T, int L, int B) {
    const int b = blockIdx.x;
    const int k = threadIdx.x;              // single wave, block = 64
    const int S = 2 * L + 1;

    const int il = in_len[b];
    const int tl = tg_len[b];
    const float4* gb = gat + (size_t)b * T * 64;
    const volatile f32x4* gv = (const volatile f32x4*)gb;  // ring-load path

    const bool v1 = (4 * k + 1 < S);
    const bool v3 = (4 * k + 3 < S);
    bool sk1 = false, sk3 = false;
    if (v1 && k > 0) {
        int tc = tgt[b * L + 2 * k], tp = tgt[b * L + 2 * k - 1];
        sk1 = (tc != 0) && (tc != tp);
    }
    if (v3) {
        int tc = tgt[b * L + 2 * k + 1], tp = tgt[b * L + 2 * k];
        sk3 = (tc != 0) && (tc != tp);
    }

    // t = 0 init (probabilities)
    float q0 = 0.0f, q1 = 0.0f, q2 = 0.0f, q3 = 0.0f;
    {
        float4 f0 = gb[k];
        if (k == 0) { q0 = f0.z; q1 = (tl > 0) ? f0.x : 0.0f; }
    }
    int acc = 0;                            // running log2 scale (integer)

    const int tmax = (il < T) ? il : T;
    const int rmax = T - 1;

    // 24-deep register prefetch ring, pinned by volatile issue order
    // (Little's law: 24 / ~600cyc latency = 1 row per 25cyc >= ~30cyc/step)
    f32x4 P[24];
    #pragma unroll
    for (int d = 0; d < 24; ++d) {
        int r = 1 + d; r = (r > rmax) ? rmax : r;
        P[d] = gv[(size_t)r * 64 + k];
    }

    int t = 1;

#define STEP(p)                                                              \
    {                                                                        \
        float qm = DPPF(q3, 0x138);          /* wave_shr:1 -> lane k-1 q3 */ \
        qm = (k == 0) ? 0.0f : qm;                                           \
        float n0 = (q0 + qm) * (p).z;                                        \
        float n1 = (q1 + q0 + (sk1 ? qm : 0.0f)) * (p).x;                    \
        float n2 = (q2 + q1) * (p).z;                                        \
        float n3 = (q3 + q2 + (sk3 ? q1 : 0.0f)) * (p).y;                    \
        q0 = n0; q1 = n1; q2 = n2; q3 = n3;                                  \
        ++t;                                                                 \
    }

// exact power-of-2 renorm: brings wave max's exponent to 0; no rounding.
#define RENORM                                                               \
    {                                                                        \
        float mx = fmaxf(fmaxf(q0, q1), fmaxf(q2, q3));                      \
        mx = fmaxf(mx, DPPF(mx, 0x111));     /* row_shr:1  */                \
        mx = fmaxf(mx, DPPF(mx, 0x112));     /* row_shr:2  */                \
        mx = fmaxf(mx, DPPF(mx, 0x114));     /* row_shr:4  */                \
        mx = fmaxf(mx, DPPF(mx, 0x118));     /* row_shr:8  */                \
        mx = fmaxf(mx, DPPF(mx, 0x142));     /* row_bcast:15 */              \
        mx = fmaxf(mx, DPPF(mx, 0x143));     /* row_bcast:31 */              \
        int me = (__builtin_amdgcn_readlane(__float_as_int(mx), 63) >> 23) & 0xff; \
        float sc = __int_as_float(((me == 0) ? 127 : (254 - me)) << 23);     \
        acc += (me == 0) ? 0 : (me - 127);                                   \
        q0 *= sc; q1 *= sc; q2 *= sc; q3 *= sc;                              \
    }

    while (t + 24 <= tmax) {
        #pragma unroll
        for (int u = 0; u < 24; ++u) {
            f32x4 p = P[u];                  // compiler waits vmcnt(oldest)
            { int r = t + 24; r = (r > rmax) ? rmax : r;
              P[u] = gv[(size_t)r * 64 + k]; }
            STEP(p)
            if ((u & 3) == 3) RENORM
        }
    }
    while (t + 4 <= tmax) {                  // remainder rows are cache-warm
        { float4 pa = gb[(size_t)t * 64 + k]; STEP(pa) }
        { float4 pb = gb[(size_t)t * 64 + k]; STEP(pb) }
        { float4 pc = gb[(size_t)t * 64 + k]; STEP(pc) }
        { float4 pd = gb[(size_t)t * 64 + k]; STEP(pd) }
        RENORM
    }
    while (t < tmax) {
        float4 pr = gb[(size_t)t * 64 + k]; STEP(pr)
    }
#undef STEP
#undef RENORM

    // final = logaddexp(alpha[2*tl], alpha[2*tl-1]) at t = il-1
    const int e1 = 2 * tl;
    const int e2 = (2 * tl - 1 > 0) ? (2 * tl - 1) : 0;
    const int i1 = e1 & 3, l1 = e1 >> 2;
    const int i2 = e2 & 3, l2 = e2 >> 2;
    float m1 = (i1 == 0) ? q0 : (i1 == 1) ? q1 : (i1 == 2) ? q2 : q3;
    float m2 = (i2 == 0) ? q0 : (i2 == 1) ? q1 : (i2 == 2) ? q2 : q3;
    float ev1 = __shfl(m1, l1, 64);
    float ev2 = __shfl(m2, l2, 64);
    float qs = ev1 + ev2;

    if (k == 0) {
        float loss = 0.0f;
        if (qs > 0.0f && il >= 1 && il <= T) {
            float fin_log2 = (float)acc + log2f(qs);
            loss = -fin_log2 * 0.6931471805599453f;      // ln2
        }
        atomicAdd(out, loss / ((float)tl * (float)B));
    }
}

extern "C" void kernel_launch(void* const* d_in, const int* in_sizes, int n_in,
                              void* d_out, int out_size, void* d_ws, size_t ws_size,
                              hipStream_t stream) {
    const float* pred = (const float*)d_in[0];
    const int*   plen = (const int*)d_in[1];
    const int*   gt   = (const int*)d_in[2];
    const int*   glen = (const int*)d_in[3];
    float* out = (float*)d_out;

    const int B = in_sizes[1];
    const int L = in_sizes[2] / B;
    const int V = 1024;                      // problem-fixed (reference setup)
    const int T = in_sizes[0] / B / V;

    float4* gat = (float4*)d_ws;             // B*T*64 float4 = ~32.8 MiB

    const int nrows = B * T;                 // one wave per row
    const int wavesPerBlk = 4;               // block = 256
    const int nblk = (nrows + wavesPerBlk - 1) / wavesPerBlk;
    lse_gather_kernel<<<nblk, 64 * wavesPerBlk, 0, stream>>>(
        pred, gt, gat, out, T, V, L, nrows);

    ctc_alpha_wave<<<B, 64, 0, stream>>>(gat, gt, plen, glen, out, T, L, B);
}

// Round 7
// 451.174 us; speedup vs baseline: 1.0539x; 1.0539x over previous
//
#include <hip/hip_runtime.h>
#include <hip/hip_bf16.h>

// DPP helper: float lane-crossing via v_mov_b32_dpp (VALU, ~4cyc; no DS).
// bound_ctrl=true -> lanes with invalid source read 0.0f.
#define DPPF(x, ctrl) \
    __int_as_float(__builtin_amdgcn_mov_dpp(__float_as_int(x), (ctrl), 0xf, 0xf, true))

// ---------------------------------------------------------------------------
// Kernel 1 (unchanged, verified): one WAVE per (b,t) row; 64 lanes x 16 = 1024.
// Emits gat[row][lane] = float4{ P(lab 2k), P(lab 2k+1), P(blank), 0 } —
// PROBABILITIES (softmax). Also zeroes out[0].
// ---------------------------------------------------------------------------
__global__ void lse_gather_kernel(const float* __restrict__ pred,
                                  const int* __restrict__ tgt,
                                  float4* __restrict__ gat,
                                  float* __restrict__ out,
                                  int T, int V, int L, int nrows) {
    if (blockIdx.x == 0 && threadIdx.x == 0) out[0] = 0.0f;

    const int wid = blockIdx.x * (blockDim.x >> 6) + (threadIdx.x >> 6);
    if (wid >= nrows) return;
    const int lane = threadIdx.x & 63;
    const int b = wid / T;

    const float* row = pred + (size_t)wid * V;   // wid == b*T + t
    float4 w0 = ((const float4*)row)[lane];
    float4 w1 = ((const float4*)row)[lane + 64];
    float4 w2 = ((const float4*)row)[lane + 128];
    float4 w3 = ((const float4*)row)[lane + 192];

    float m = fmaxf(fmaxf(fmaxf(w0.x, w0.y), fmaxf(w0.z, w0.w)),
                    fmaxf(fmaxf(w1.x, w1.y), fmaxf(w1.z, w1.w)));
    m = fmaxf(m, fmaxf(fmaxf(w2.x, w2.y), fmaxf(w2.z, w2.w)));
    m = fmaxf(m, fmaxf(fmaxf(w3.x, w3.y), fmaxf(w3.z, w3.w)));
    #pragma unroll
    for (int off = 1; off < 64; off <<= 1) m = fmaxf(m, __shfl_xor(m, off, 64));

    float s = __expf(w0.x - m) + __expf(w0.y - m) + __expf(w0.z - m) + __expf(w0.w - m)
            + __expf(w1.x - m) + __expf(w1.y - m) + __expf(w1.z - m) + __expf(w1.w - m)
            + __expf(w2.x - m) + __expf(w2.y - m) + __expf(w2.z - m) + __expf(w2.w - m)
            + __expf(w3.x - m) + __expf(w3.y - m) + __expf(w3.z - m) + __expf(w3.w - m);
    #pragma unroll
    for (int off = 1; off < 64; off <<= 1) s += __shfl_xor(s, off, 64);

    const float lse = m + __logf(s);

    float pz = __expf(row[0] - lse);        // blank probability
    float px = 0.0f, py = 0.0f;             // 0 = additive identity: masks
    const int l0 = 2 * lane, l1i = 2 * lane + 1;
    if (l0  < L) px = __expf(row[tgt[b * L + l0 ]] - lse);  // row is L1-hot
    if (l1i < L) py = __expf(row[tgt[b * L + l1i]] - lse);

    float4 o; o.x = px; o.y = py; o.z = pz; o.w = 0.0f;
    gat[(size_t)wid * 64 + lane] = o;
}

// ---------------------------------------------------------------------------
// Kernel 2: CTC alpha, ONE WAVE per batch element, LINEAR (prob) domain.
// EXACT round-4 verified math (passing, 81us). ONE mechanism change:
// __builtin_amdgcn_sched_barrier(0) after every ring-load issue. History:
//   r0/r4: compiled loads  -> sunk to use (VGPR=44), 200cyc/step exposed
//   r5:    hand-asm ring   -> GPU fault (unverifiable codegen hazards)
//   r6:    volatile loads  -> strictly ordered, SERIALIZED, 690cyc/step
// sched_barrier(0) is the designed tool: a scheduling fence no instruction
// may cross, so each load is pinned at its issue slot (24 in flight), while
// waitcnt insertion / RA / hazards stay fully compiler-owned.
// Diagnostic: VGPR_Count 44 -> >=140 iff the ring is physically resident.
// ---------------------------------------------------------------------------
__global__ __launch_bounds__(64, 1)
void ctc_alpha_wave(const float4* __restrict__ gat,
                    const int* __restrict__ tgt,
                    const int* __restrict__ in_len,
                    const int* __restrict__ tg_len,
                    float* __restrict__ out,
                    int T, int L, int B) {
    const int b = blockIdx.x;
    const int k = threadIdx.x;              // single wave, block = 64
    const int S = 2 * L + 1;

    const int il = in_len[b];
    const int tl = tg_len[b];
    const float4* gb = gat + (size_t)b * T * 64;

    const bool v1 = (4 * k + 1 < S);
    const bool v3 = (4 * k + 3 < S);
    bool sk1 = false, sk3 = false;
    if (v1 && k > 0) {
        int tc = tgt[b * L + 2 * k], tp = tgt[b * L + 2 * k - 1];
        sk1 = (tc != 0) && (tc != tp);
    }
    if (v3) {
        int tc = tgt[b * L + 2 * k + 1], tp = tgt[b * L + 2 * k];
        sk3 = (tc != 0) && (tc != tp);
    }

    // t = 0 init (probabilities)
    float q0 = 0.0f, q1 = 0.0f, q2 = 0.0f, q3 = 0.0f;
    {
        float4 f0 = gb[k];
        if (k == 0) { q0 = f0.z; q1 = (tl > 0) ? f0.x : 0.0f; }
    }
    int acc = 0;                            // running log2 scale (integer)

    const int tmax = (il < T) ? il : T;
    const int rmax = T - 1;

    // 24-deep register prefetch ring; sched_barrier(0) after each issue pins
    // the load in its scheduling region -> physically 24 in flight.
    // (Little's law: 24 / ~900cyc HBM latency = 1 row per 37cyc)
    float4 P[24];
    #pragma unroll
    for (int d = 0; d < 24; ++d) {
        int r = 1 + d; r = (r > rmax) ? rmax : r;
        P[d] = gb[(size_t)r * 64 + k];
        __builtin_amdgcn_sched_barrier(0);
    }

    int t = 1;

#define STEP(p)                                                              \
    {                                                                        \
        float qm = DPPF(q3, 0x138);          /* wave_shr:1 -> lane k-1 q3 */ \
        qm = (k == 0) ? 0.0f : qm;                                           \
        float n0 = (q0 + qm) * (p).z;                                        \
        float n1 = (q1 + q0 + (sk1 ? qm : 0.0f)) * (p).x;                    \
        float n2 = (q2 + q1) * (p).z;                                        \
        float n3 = (q3 + q2 + (sk3 ? q1 : 0.0f)) * (p).y;                    \
        q0 = n0; q1 = n1; q2 = n2; q3 = n3;                                  \
        ++t;                                                                 \
    }

// exact power-of-2 renorm: brings wave max's exponent to 0; no rounding.
#define RENORM                                                               \
    {                                                                        \
        float mx = fmaxf(fmaxf(q0, q1), fmaxf(q2, q3));                      \
        mx = fmaxf(mx, DPPF(mx, 0x111));     /* row_shr:1  */                \
        mx = fmaxf(mx, DPPF(mx, 0x112));     /* row_shr:2  */                \
        mx = fmaxf(mx, DPPF(mx, 0x114));     /* row_shr:4  */                \
        mx = fmaxf(mx, DPPF(mx, 0x118));     /* row_shr:8  */                \
        mx = fmaxf(mx, DPPF(mx, 0x142));     /* row_bcast:15 */              \
        mx = fmaxf(mx, DPPF(mx, 0x143));     /* row_bcast:31 */              \
        int me = (__builtin_amdgcn_readlane(__float_as_int(mx), 63) >> 23) & 0xff; \
        float sc = __int_as_float(((me == 0) ? 127 : (254 - me)) << 23);     \
        acc += (me == 0) ? 0 : (me - 127);                                   \
        q0 *= sc; q1 *= sc; q2 *= sc; q3 *= sc;                              \
    }

    while (t + 24 <= tmax) {
        #pragma unroll
        for (int u = 0; u < 24; ++u) {
            float4 p = P[u];                 // waits only this slot's load
            { int r = t + 24; r = (r > rmax) ? rmax : r;
              P[u] = gb[(size_t)r * 64 + k]; }
            __builtin_amdgcn_sched_barrier(0);  // load cannot sink past here
            STEP(p)
            if ((u & 3) == 3) RENORM
        }
    }
    while (t + 4 <= tmax) {                  // remainder rows are cache-warm
        { float4 pa = gb[(size_t)t * 64 + k]; STEP(pa) }
        { float4 pb = gb[(size_t)t * 64 + k]; STEP(pb) }
        { float4 pc = gb[(size_t)t * 64 + k]; STEP(pc) }
        { float4 pd = gb[(size_t)t * 64 + k]; STEP(pd) }
        RENORM
    }
    while (t < tmax) {
        float4 pr = gb[(size_t)t * 64 + k]; STEP(pr)
    }
#undef STEP
#undef RENORM

    // final = logaddexp(alpha[2*tl], alpha[2*tl-1]) at t = il-1
    const int e1 = 2 * tl;
    const int e2 = (2 * tl - 1 > 0) ? (2 * tl - 1) : 0;
    const int i1 = e1 & 3, l1 = e1 >> 2;
    const int i2 = e2 & 3, l2 = e2 >> 2;
    float m1 = (i1 == 0) ? q0 : (i1 == 1) ? q1 : (i1 == 2) ? q2 : q3;
    float m2 = (i2 == 0) ? q0 : (i2 == 1) ? q1 : (i2 == 2) ? q2 : q3;
    float ev1 = __shfl(m1, l1, 64);
    float ev2 = __shfl(m2, l2, 64);
    float qs = ev1 + ev2;

    if (k == 0) {
        float loss = 0.0f;
        if (qs > 0.0f && il >= 1 && il <= T) {
            float fin_log2 = (float)acc + log2f(qs);
            loss = -fin_log2 * 0.6931471805599453f;      // ln2
        }
        atomicAdd(out, loss / ((float)tl * (float)B));
    }
}

extern "C" void kernel_launch(void* const* d_in, const int* in_sizes, int n_in,
                              void* d_out, int out_size, void* d_ws, size_t ws_size,
                              hipStream_t stream) {
    const float* pred = (const float*)d_in[0];
    const int*   plen = (const int*)d_in[1];
    const int*   gt   = (const int*)d_in[2];
    const int*   glen = (const int*)d_in[3];
    float* out = (float*)d_out;

    const int B = in_sizes[1];
    const int L = in_sizes[2] / B;
    const int V = 1024;                      // problem-fixed (reference setup)
    const int T = in_sizes[0] / B / V;

    float4* gat = (float4*)d_ws;             // B*T*64 float4 = ~32.8 MiB

    const int nrows = B * T;                 // one wave per row
    const int wavesPerBlk = 4;               // block = 256
    const int nblk = (nrows + wavesPerBlk - 1) / wavesPerBlk;
    lse_gather_kernel<<<nblk, 64 * wavesPerBlk, 0, stream>>>(
        pred, gt, gat, out, T, V, L, nrows);

    ctc_alpha_wave<<<B, 64, 0, stream>>>(gat, gt, plen, glen, out, T, L, B);
}

// Round 8
// 425.347 us; speedup vs baseline: 1.1179x; 1.0607x over previous
//
#include <hip/hip_runtime.h>
#include <hip/hip_bf16.h>

// DPP helper: float lane-crossing via v_mov_b32_dpp (VALU, ~4cyc; no DS).
// bound_ctrl=true -> lanes with invalid source read 0.0f.
#define DPPF(x, ctrl) \
    __int_as_float(__builtin_amdgcn_mov_dpp(__float_as_int(x), (ctrl), 0xf, 0xf, true))

// async global->LDS DMA: 16B/lane; LDS dest = wave-uniform base + lane*16,
// global src per-lane. Counted by vmcnt. (T3/T4 pattern; r1's failure was
// 67.6KB static LDS -> launch never happened, mechanism never tested.)
typedef __attribute__((address_space(1))) unsigned int u32_g;
typedef __attribute__((address_space(3))) unsigned int u32_l;
__device__ __forceinline__ void gload_lds16(const void* g, void* l) {
    __builtin_amdgcn_global_load_lds((const u32_g*)g, (u32_l*)l, 16, 0, 0);
}

// ---------------------------------------------------------------------------
// Kernel 1 (unchanged, verified): one WAVE per (b,t) row; 64 lanes x 16 = 1024.
// Emits gat[row][lane] = float4{ P(lab 2k), P(lab 2k+1), P(blank), 0 } —
// PROBABILITIES (softmax). Also zeroes out[0].
// ---------------------------------------------------------------------------
__global__ void lse_gather_kernel(const float* __restrict__ pred,
                                  const int* __restrict__ tgt,
                                  float4* __restrict__ gat,
                                  float* __restrict__ out,
                                  int T, int V, int L, int nrows) {
    if (blockIdx.x == 0 && threadIdx.x == 0) out[0] = 0.0f;

    const int wid = blockIdx.x * (blockDim.x >> 6) + (threadIdx.x >> 6);
    if (wid >= nrows) return;
    const int lane = threadIdx.x & 63;
    const int b = wid / T;

    const float* row = pred + (size_t)wid * V;   // wid == b*T + t
    float4 w0 = ((const float4*)row)[lane];
    float4 w1 = ((const float4*)row)[lane + 64];
    float4 w2 = ((const float4*)row)[lane + 128];
    float4 w3 = ((const float4*)row)[lane + 192];

    float m = fmaxf(fmaxf(fmaxf(w0.x, w0.y), fmaxf(w0.z, w0.w)),
                    fmaxf(fmaxf(w1.x, w1.y), fmaxf(w1.z, w1.w)));
    m = fmaxf(m, fmaxf(fmaxf(w2.x, w2.y), fmaxf(w2.z, w2.w)));
    m = fmaxf(m, fmaxf(fmaxf(w3.x, w3.y), fmaxf(w3.z, w3.w)));
    #pragma unroll
    for (int off = 1; off < 64; off <<= 1) m = fmaxf(m, __shfl_xor(m, off, 64));

    float s = __expf(w0.x - m) + __expf(w0.y - m) + __expf(w0.z - m) + __expf(w0.w - m)
            + __expf(w1.x - m) + __expf(w1.y - m) + __expf(w1.z - m) + __expf(w1.w - m)
            + __expf(w2.x - m) + __expf(w2.y - m) + __expf(w2.z - m) + __expf(w2.w - m)
            + __expf(w3.x - m) + __expf(w3.y - m) + __expf(w3.z - m) + __expf(w3.w - m);
    #pragma unroll
    for (int off = 1; off < 64; off <<= 1) s += __shfl_xor(s, off, 64);

    const float lse = m + __logf(s);

    float pz = __expf(row[0] - lse);        // blank probability
    float px = 0.0f, py = 0.0f;             // 0 = additive identity: masks
    const int l0 = 2 * lane, l1i = 2 * lane + 1;
    if (l0  < L) px = __expf(row[tgt[b * L + l0 ]] - lse);  // row is L1-hot
    if (l1i < L) py = __expf(row[tgt[b * L + l1i]] - lse);

    float4 o; o.x = px; o.y = py; o.z = pz; o.w = 0.0f;
    gat[(size_t)wid * 64 + lane] = o;
}

// ---------------------------------------------------------------------------
// Kernel 2: CTC alpha, ONE WAVE per batch element, LINEAR (prob) domain.
// EXACT round-4 verified math. Memory path = 32-slot LDS DMA ring:
//   - 29 global_load_lds issued ahead (26 pending steady-state; Little's
//     law: 26/~600cyc = 1 row per 23cyc >= ~45cyc/step consumption)
//   - per-step counted `s_waitcnt vmcnt(25)` retires exactly row t+3
//   - ds_read prefetched 3 steps ahead via named regs pA/pB/pC (static
//     indexing, rule #20) so ~120cyc LDS latency hides under 3 steps
//   - slot r&31; DMA at step t writes slot (t-3)&31, which was ds_read at
//     step t-6 -> 6 steps of slack, no live-slot overwrite (steady loop
//     bound t+32<=rmax keeps every in-loop DMA row unclamped/exact)
// vmcnt accounting is exact: inside the loop the ONLY VMEM ops are our DMAs
// (STEP/RENORM are VALU; row data comes from LDS), and `"memory"`-clobbered
// asm waits order all memory ops. No VGPR-destination loads to sink (r0-r7
// ring failures) and no asm register write-back hazards (r5 fault).
// Diagnostic: LDS_Block_Size = 32768.
// ---------------------------------------------------------------------------
__global__ __launch_bounds__(64, 1)
void ctc_alpha_wave(const float4* __restrict__ gat,
                    const int* __restrict__ tgt,
                    const int* __restrict__ in_len,
                    const int* __restrict__ tg_len,
                    float* __restrict__ out,
                    int T, int L, int B) {
    __shared__ float4 ring[32][64];         // 32 KiB staging ring

    const int b = blockIdx.x;
    const int k = threadIdx.x;              // single wave, block = 64
    const int S = 2 * L + 1;

    const int il = in_len[b];
    const int tl = tg_len[b];
    const float4* gb = gat + (size_t)b * T * 64;

    const bool v1 = (4 * k + 1 < S);
    const bool v3 = (4 * k + 3 < S);
    bool sk1 = false, sk3 = false;
    if (v1 && k > 0) {
        int tc = tgt[b * L + 2 * k], tp = tgt[b * L + 2 * k - 1];
        sk1 = (tc != 0) && (tc != tp);
    }
    if (v3) {
        int tc = tgt[b * L + 2 * k + 1], tp = tgt[b * L + 2 * k];
        sk3 = (tc != 0) && (tc != tp);
    }

    // t = 0 init (probabilities)
    float q0 = 0.0f, q1 = 0.0f, q2 = 0.0f, q3 = 0.0f;
    {
        float4 f0 = gb[k];
        if (k == 0) { q0 = f0.z; q1 = (tl > 0) ? f0.x : 0.0f; }
    }
    int acc = 0;                            // running log2 scale (integer)

    const int tmax = (il < T) ? il : T;
    const int rmax = T - 1;

    // clean vmcnt slate: compiled loads (f0, tgt) retired before the ring
    asm volatile("s_waitcnt vmcnt(0)" ::: "memory");

    // prologue: issue rows 1..29 (29 DMAs; clamped dups only matter when the
    // steady loop can't run, and then LDS is never read — tail is direct)
    #pragma unroll
    for (int d = 1; d <= 29; ++d) {
        int r = (d > rmax) ? rmax : d;
        gload_lds16(&gb[(size_t)r * 64 + k], &ring[r & 31][0]);
    }
    // rows 1..3 landed (pending = rows 4..29 = 26)
    asm volatile("s_waitcnt vmcnt(26)" ::: "memory");
    float4 pA = ring[1][k];                 // row t
    float4 pB = ring[2][k];                 // row t+1
    float4 pC = ring[3][k];                 // row t+2

    int t = 1;

#define STEP(p)                                                              \
    {                                                                        \
        float qm = DPPF(q3, 0x138);          /* wave_shr:1 -> lane k-1 q3 */ \
        qm = (k == 0) ? 0.0f : qm;                                           \
        float n0 = (q0 + qm) * (p).z;                                        \
        float n1 = (q1 + q0 + (sk1 ? qm : 0.0f)) * (p).x;                    \
        float n2 = (q2 + q1) * (p).z;                                        \
        float n3 = (q3 + q2 + (sk3 ? q1 : 0.0f)) * (p).y;                    \
        q0 = n0; q1 = n1; q2 = n2; q3 = n3;                                  \
        ++t;                                                                 \
    }

// exact power-of-2 renorm: brings wave max's exponent to 0; no rounding.
#define RENORM                                                               \
    {                                                                        \
        float mx = fmaxf(fmaxf(q0, q1), fmaxf(q2, q3));                      \
        mx = fmaxf(mx, DPPF(mx, 0x111));     /* row_shr:1  */                \
        mx = fmaxf(mx, DPPF(mx, 0x112));     /* row_shr:2  */                \
        mx = fmaxf(mx, DPPF(mx, 0x114));     /* row_shr:4  */                \
        mx = fmaxf(mx, DPPF(mx, 0x118));     /* row_shr:8  */                \
        mx = fmaxf(mx, DPPF(mx, 0x142));     /* row_bcast:15 */              \
        mx = fmaxf(mx, DPPF(mx, 0x143));     /* row_bcast:31 */              \
        int me = (__builtin_amdgcn_readlane(__float_as_int(mx), 63) >> 23) & 0xff; \
        float sc = __int_as_float(((me == 0) ? 127 : (254 - me)) << 23);     \
        acc += (me == 0) ? 0 : (me - 127);                                   \
        q0 *= sc; q1 *= sc; q2 *= sc; q3 *= sc;                              \
    }

    // steady state: invariant at top of step t — pending DMAs = rows
    // t+3..t+28 (26). vmcnt(25) -> row t+3 landed. All rows exact (unclamped).
    while (t + 4 <= tmax && t + 32 <= rmax) {
        #pragma unroll
        for (int u = 0; u < 4; ++u) {
            asm volatile("s_waitcnt vmcnt(25)" ::: "memory");
            float4 pN = ring[(t + 3) & 31][k];
            gload_lds16(&gb[(size_t)(t + 29) * 64 + k], &ring[(t + 29) & 31][0]);
            STEP(pA)
            pA = pB; pB = pC; pC = pN;
        }
        RENORM
    }

    // drain ring; tail uses direct global loads (verified round-4 path)
    asm volatile("s_waitcnt vmcnt(0)" ::: "memory");

    while (t + 4 <= tmax) {
        { float4 pa = gb[(size_t)t * 64 + k]; STEP(pa) }
        { float4 pb = gb[(size_t)t * 64 + k]; STEP(pb) }
        { float4 pc = gb[(size_t)t * 64 + k]; STEP(pc) }
        { float4 pd = gb[(size_t)t * 64 + k]; STEP(pd) }
        RENORM
    }
    while (t < tmax) {
        float4 pr = gb[(size_t)t * 64 + k]; STEP(pr)
    }
#undef STEP
#undef RENORM

    // final = logaddexp(alpha[2*tl], alpha[2*tl-1]) at t = il-1
    const int e1 = 2 * tl;
    const int e2 = (2 * tl - 1 > 0) ? (2 * tl - 1) : 0;
    const int i1 = e1 & 3, l1 = e1 >> 2;
    const int i2 = e2 & 3, l2 = e2 >> 2;
    float m1 = (i1 == 0) ? q0 : (i1 == 1) ? q1 : (i1 == 2) ? q2 : q3;
    float m2 = (i2 == 0) ? q0 : (i2 == 1) ? q1 : (i2 == 2) ? q2 : q3;
    float ev1 = __shfl(m1, l1, 64);
    float ev2 = __shfl(m2, l2, 64);
    float qs = ev1 + ev2;

    if (k == 0) {
        float loss = 0.0f;
        if (qs > 0.0f && il >= 1 && il <= T) {
            float fin_log2 = (float)acc + log2f(qs);
            loss = -fin_log2 * 0.6931471805599453f;      // ln2
        }
        atomicAdd(out, loss / ((float)tl * (float)B));
    }
}

extern "C" void kernel_launch(void* const* d_in, const int* in_sizes, int n_in,
                              void* d_out, int out_size, void* d_ws, size_t ws_size,
                              hipStream_t stream) {
    const float* pred = (const float*)d_in[0];
    const int*   plen = (const int*)d_in[1];
    const int*   gt   = (const int*)d_in[2];
    const int*   glen = (const int*)d_in[3];
    float* out = (float*)d_out;

    const int B = in_sizes[1];
    const int L = in_sizes[2] / B;
    const int V = 1024;                      // problem-fixed (reference setup)
    const int T = in_sizes[0] / B / V;

    float4* gat = (float4*)d_ws;             // B*T*64 float4 = ~32.8 MiB

    const int nrows = B * T;                 // one wave per row
    const int wavesPerBlk = 4;               // block = 256
    const int nblk = (nrows + wavesPerBlk - 1) / wavesPerBlk;
    lse_gather_kernel<<<nblk, 64 * wavesPerBlk, 0, stream>>>(
        pred, gt, gat, out, T, V, L, nrows);

    ctc_alpha_wave<<<B, 64, 0, stream>>>(gat, gt, plen, glen, out, T, L, B);
}

// Round 10
// 251.639 us; speedup vs baseline: 1.8895x; 1.6903x over previous
//
#include <hip/hip_runtime.h>
#include <hip/hip_bf16.h>

// DPP helper: float lane-crossing via v_mov_b32_dpp (VALU, ~4cyc; no DS).
// bound_ctrl=true -> lanes with invalid source read 0.0f.
#define DPPF(x, ctrl) \
    __int_as_float(__builtin_amdgcn_mov_dpp(__float_as_int(x), (ctrl), 0xf, 0xf, true))

// ---------------------------------------------------------------------------
// Kernel 1 (unchanged, verified): one WAVE per (b,t) row; 64 lanes x 16 = 1024.
// Emits gat[row][lane] = float4{ P(lab 2k), P(lab 2k+1), P(blank), 0 } —
// PROBABILITIES (softmax). Also zeroes out[0].
// ---------------------------------------------------------------------------
__global__ void lse_gather_kernel(const float* __restrict__ pred,
                                  const int* __restrict__ tgt,
                                  float4* __restrict__ gat,
                                  float* __restrict__ out,
                                  int T, int V, int L, int nrows) {
    if (blockIdx.x == 0 && threadIdx.x == 0) out[0] = 0.0f;

    const int wid = blockIdx.x * (blockDim.x >> 6) + (threadIdx.x >> 6);
    if (wid >= nrows) return;
    const int lane = threadIdx.x & 63;
    const int b = wid / T;

    const float* row = pred + (size_t)wid * V;   // wid == b*T + t
    float4 w0 = ((const float4*)row)[lane];
    float4 w1 = ((const float4*)row)[lane + 64];
    float4 w2 = ((const float4*)row)[lane + 128];
    float4 w3 = ((const float4*)row)[lane + 192];

    float m = fmaxf(fmaxf(fmaxf(w0.x, w0.y), fmaxf(w0.z, w0.w)),
                    fmaxf(fmaxf(w1.x, w1.y), fmaxf(w1.z, w1.w)));
    m = fmaxf(m, fmaxf(fmaxf(w2.x, w2.y), fmaxf(w2.z, w2.w)));
    m = fmaxf(m, fmaxf(fmaxf(w3.x, w3.y), fmaxf(w3.z, w3.w)));
    #pragma unroll
    for (int off = 1; off < 64; off <<= 1) m = fmaxf(m, __shfl_xor(m, off, 64));

    float s = __expf(w0.x - m) + __expf(w0.y - m) + __expf(w0.z - m) + __expf(w0.w - m)
            + __expf(w1.x - m) + __expf(w1.y - m) + __expf(w1.z - m) + __expf(w1.w - m)
            + __expf(w2.x - m) + __expf(w2.y - m) + __expf(w2.z - m) + __expf(w2.w - m)
            + __expf(w3.x - m) + __expf(w3.y - m) + __expf(w3.z - m) + __expf(w3.w - m);
    #pragma unroll
    for (int off = 1; off < 64; off <<= 1) s += __shfl_xor(s, off, 64);

    const float lse = m + __logf(s);

    float pz = __expf(row[0] - lse);        // blank probability
    float px = 0.0f, py = 0.0f;             // 0 = additive identity: masks
    const int l0 = 2 * lane, l1i = 2 * lane + 1;
    if (l0  < L) px = __expf(row[tgt[b * L + l0 ]] - lse);  // row is L1-hot
    if (l1i < L) py = __expf(row[tgt[b * L + l1i]] - lse);

    float4 o; o.x = px; o.y = py; o.z = pz; o.w = 0.0f;
    gat[(size_t)wid * 64 + lane] = o;
}

// ---------------------------------------------------------------------------
// Kernel 2: CTC alpha with a PREFETCH HELPER WAVE (block = 128 = 2 waves).
//   wave 0 (consumer): EXACT round-4 verified math, direct loads, chunked
//     into 16-step chunks with __syncthreads() at each boundary.
//   wave 1 (prefetcher): during chunk c, burst-loads chunk c+1's 16 rows;
//     one component of each row is folded into a scalar that an empty asm
//     consumes (rule #17 anti-DCE; r9 fix: "v" takes SCALARS, not float4).
//     Warms per-CU L1/L2 (16KB/chunk ahead + 16KB current fits 32KB L1).
// Rationale: r0..r8 proved every HIP-level deep-pipeline mechanism is
// defeated (sink / scratch-demotion / waitcnt re-drain / serialization /
// fault). So keep the compiler's natural ~3-deep pipeline and SHORTEN THE
// LATENCY instead: FETCH_SIZE shows ~half the consumer loads miss to HBM
// (~900cyc); with L1/L2-warm data latency ~100-200cyc -> ~35-70cyc/step.
// Barrier safety: both waves compute nc from the same uniform il; wave 1
// exits after exactly nc barriers; consumer tail has no barriers.
// ---------------------------------------------------------------------------
__global__ __launch_bounds__(128, 1)
void ctc_alpha_wave(const float4* __restrict__ gat,
                    const int* __restrict__ tgt,
                    const int* __restrict__ in_len,
                    const int* __restrict__ tg_len,
                    float* __restrict__ out,
                    int T, int L, int B) {
    const int b = blockIdx.x;
    const int w = threadIdx.x >> 6;         // 0 = consumer, 1 = prefetcher
    const int k = threadIdx.x & 63;
    const int S = 2 * L + 1;

    const int il = in_len[b];
    const int tl = tg_len[b];
    const float4* gb = gat + (size_t)b * T * 64;

    const int tmax = (il < T) ? il : T;
    const int rmax = T - 1;
    const int nsteps = tmax - 1;            // steps t = 1 .. tmax-1
    const int nc = (nsteps >= 16) ? (nsteps >> 4) : 0;   // full 16-step chunks

    if (w == 1) {
        // ---- prefetch wave: chunk c -> rows of chunk c+1, burst of 16 ----
        for (int c = 0; c < nc; ++c) {
            const int base = 1 + 16 * (c + 1);
            float4 f0, f1, f2, f3, f4, f5, f6, f7;
            float4 f8, f9, fa, fb, fc, fd, fe, ff;
#define PF(var, j) { int r = base + (j); r = (r > rmax) ? rmax : r;          \
                     var = gb[(size_t)r * 64 + k]; }
            PF(f0, 0)  PF(f1, 1)  PF(f2, 2)  PF(f3, 3)
            PF(f4, 4)  PF(f5, 5)  PF(f6, 6)  PF(f7, 7)
            PF(f8, 8)  PF(f9, 9)  PF(fa, 10) PF(fb, 11)
            PF(fc, 12) PF(fd, 13) PF(fe, 14) PF(ff, 15)
#undef PF
            // fold to ONE scalar (legal "v" operand); depends on all 16 rows
            // -> none of the loads can be DCE'd. 15 adds per 16 steps ~ free.
            float keep = ((f0.x + f1.x) + (f2.x + f3.x))
                       + ((f4.x + f5.x) + (f6.x + f7.x))
                       + ((f8.x + f9.x) + (fa.x + fb.x))
                       + ((fc.x + fd.x) + (fe.x + ff.x));
            asm volatile("" :: "v"(keep));
            __syncthreads();
        }
        return;                             // no barriers after this point
    }

    // ---- consumer wave (round-4 verified math) ----
    const bool v1 = (4 * k + 1 < S);
    const bool v3 = (4 * k + 3 < S);
    bool sk1 = false, sk3 = false;
    if (v1 && k > 0) {
        int tc = tgt[b * L + 2 * k], tp = tgt[b * L + 2 * k - 1];
        sk1 = (tc != 0) && (tc != tp);
    }
    if (v3) {
        int tc = tgt[b * L + 2 * k + 1], tp = tgt[b * L + 2 * k];
        sk3 = (tc != 0) && (tc != tp);
    }

    // t = 0 init (probabilities)
    float q0 = 0.0f, q1 = 0.0f, q2 = 0.0f, q3 = 0.0f;
    {
        float4 f0 = gb[k];
        if (k == 0) { q0 = f0.z; q1 = (tl > 0) ? f0.x : 0.0f; }
    }
    int acc = 0;                            // running log2 scale (integer)

    int t = 1;

#define STEP(p)                                                              \
    {                                                                        \
        float qm = DPPF(q3, 0x138);          /* wave_shr:1 -> lane k-1 q3 */ \
        qm = (k == 0) ? 0.0f : qm;                                           \
        float n0 = (q0 + qm) * (p).z;                                        \
        float n1 = (q1 + q0 + (sk1 ? qm : 0.0f)) * (p).x;                    \
        float n2 = (q2 + q1) * (p).z;                                        \
        float n3 = (q3 + q2 + (sk3 ? q1 : 0.0f)) * (p).y;                    \
        q0 = n0; q1 = n1; q2 = n2; q3 = n3;                                  \
        ++t;                                                                 \
    }

// exact power-of-2 renorm: brings wave max's exponent to 0; no rounding.
#define RENORM                                                               \
    {                                                                        \
        float mx = fmaxf(fmaxf(q0, q1), fmaxf(q2, q3));                      \
        mx = fmaxf(mx, DPPF(mx, 0x111));     /* row_shr:1  */                \
        mx = fmaxf(mx, DPPF(mx, 0x112));     /* row_shr:2  */                \
        mx = fmaxf(mx, DPPF(mx, 0x114));     /* row_shr:4  */                \
        mx = fmaxf(mx, DPPF(mx, 0x118));     /* row_shr:8  */                \
        mx = fmaxf(mx, DPPF(mx, 0x142));     /* row_bcast:15 */              \
        mx = fmaxf(mx, DPPF(mx, 0x143));     /* row_bcast:31 */              \
        int me = (__builtin_amdgcn_readlane(__float_as_int(mx), 63) >> 23) & 0xff; \
        float sc = __int_as_float(((me == 0) ? 127 : (254 - me)) << 23);     \
        acc += (me == 0) ? 0 : (me - 127);                                   \
        q0 *= sc; q1 *= sc; q2 *= sc; q3 *= sc;                              \
    }

    // chunked main loop: 16 steps per chunk, barrier at each boundary
    // (prefetcher is loading chunk c+1 concurrently)
    for (int c = 0; c < nc; ++c) {
        #pragma unroll
        for (int g = 0; g < 4; ++g) {
            { float4 pa = gb[(size_t)t * 64 + k]; STEP(pa) }
            { float4 pb = gb[(size_t)t * 64 + k]; STEP(pb) }
            { float4 pc = gb[(size_t)t * 64 + k]; STEP(pc) }
            { float4 pd = gb[(size_t)t * 64 + k]; STEP(pd) }
            RENORM
        }
        __syncthreads();
    }

    // tail (< 16 steps), verified round-4 path
    while (t + 4 <= tmax) {
        { float4 pa = gb[(size_t)t * 64 + k]; STEP(pa) }
        { float4 pb = gb[(size_t)t * 64 + k]; STEP(pb) }
        { float4 pc = gb[(size_t)t * 64 + k]; STEP(pc) }
        { float4 pd = gb[(size_t)t * 64 + k]; STEP(pd) }
        RENORM
    }
    while (t < tmax) {
        float4 pr = gb[(size_t)t * 64 + k]; STEP(pr)
    }
#undef STEP
#undef RENORM

    // final = logaddexp(alpha[2*tl], alpha[2*tl-1]) at t = il-1
    const int e1 = 2 * tl;
    const int e2 = (2 * tl - 1 > 0) ? (2 * tl - 1) : 0;
    const int i1 = e1 & 3, l1 = e1 >> 2;
    const int i2 = e2 & 3, l2 = e2 >> 2;
    float m1 = (i1 == 0) ? q0 : (i1 == 1) ? q1 : (i1 == 2) ? q2 : q3;
    float m2 = (i2 == 0) ? q0 : (i2 == 1) ? q1 : (i2 == 2) ? q2 : q3;
    float ev1 = __shfl(m1, l1, 64);
    float ev2 = __shfl(m2, l2, 64);
    float qs = ev1 + ev2;

    if (k == 0) {
        float loss = 0.0f;
        if (qs > 0.0f && il >= 1 && il <= T) {
            float fin_log2 = (float)acc + log2f(qs);
            loss = -fin_log2 * 0.6931471805599453f;      // ln2
        }
        atomicAdd(out, loss / ((float)tl * (float)B));
    }
}

extern "C" void kernel_launch(void* const* d_in, const int* in_sizes, int n_in,
                              void* d_out, int out_size, void* d_ws, size_t ws_size,
                              hipStream_t stream) {
    const float* pred = (const float*)d_in[0];
    const int*   plen = (const int*)d_in[1];
    const int*   gt   = (const int*)d_in[2];
    const int*   glen = (const int*)d_in[3];
    float* out = (float*)d_out;

    const int B = in_sizes[1];
    const int L = in_sizes[2] / B;
    const int V = 1024;                      // problem-fixed (reference setup)
    const int T = in_sizes[0] / B / V;

    float4* gat = (float4*)d_ws;             // B*T*64 float4 = ~32.8 MiB

    const int nrows = B * T;                 // one wave per row
    const int wavesPerBlk = 4;               // block = 256
    const int nblk = (nrows + wavesPerBlk - 1) / wavesPerBlk;
    lse_gather_kernel<<<nblk, 64 * wavesPerBlk, 0, stream>>>(
        pred, gt, gat, out, T, V, L, nrows);

    ctc_alpha_wave<<<B, 128, 0, stream>>>(gat, gt, plen, glen, out, T, L, B);
}

// Round 11
// 245.223 us; speedup vs baseline: 1.9390x; 1.0262x over previous
//
#include <hip/hip_runtime.h>
#include <hip/hip_bf16.h>

// DPP helper: float lane-crossing via v_mov_b32_dpp (VALU, ~4cyc; no DS).
// bound_ctrl=true -> lanes with invalid source read 0.0f.
#define DPPF(x, ctrl) \
    __int_as_float(__builtin_amdgcn_mov_dpp(__float_as_int(x), (ctrl), 0xf, 0xf, true))

// async global->LDS DMA: 16B/lane; LDS dest = wave-uniform base + lane*16.
// Mechanically verified in r8 (data landed correctly; r8's slowness was the
// ISSUING wave's compiler-inserted vmcnt(0) before its own ds_reads).
typedef __attribute__((address_space(1))) unsigned int u32_g;
typedef __attribute__((address_space(3))) unsigned int u32_l;
__device__ __forceinline__ void gload_lds16(const void* g, void* l) {
    __builtin_amdgcn_global_load_lds((const u32_g*)g, (u32_l*)l, 16, 0, 0);
}

// ---------------------------------------------------------------------------
// Kernel 1 (unchanged, verified): one WAVE per (b,t) row; 64 lanes x 16 = 1024.
// Emits gat[row][lane] = float4{ P(lab 2k), P(lab 2k+1), P(blank), 0 } —
// PROBABILITIES (softmax). Also zeroes out[0].
// ---------------------------------------------------------------------------
__global__ void lse_gather_kernel(const float* __restrict__ pred,
                                  const int* __restrict__ tgt,
                                  float4* __restrict__ gat,
                                  float* __restrict__ out,
                                  int T, int V, int L, int nrows) {
    if (blockIdx.x == 0 && threadIdx.x == 0) out[0] = 0.0f;

    const int wid = blockIdx.x * (blockDim.x >> 6) + (threadIdx.x >> 6);
    if (wid >= nrows) return;
    const int lane = threadIdx.x & 63;
    const int b = wid / T;

    const float* row = pred + (size_t)wid * V;   // wid == b*T + t
    float4 w0 = ((const float4*)row)[lane];
    float4 w1 = ((const float4*)row)[lane + 64];
    float4 w2 = ((const float4*)row)[lane + 128];
    float4 w3 = ((const float4*)row)[lane + 192];

    float m = fmaxf(fmaxf(fmaxf(w0.x, w0.y), fmaxf(w0.z, w0.w)),
                    fmaxf(fmaxf(w1.x, w1.y), fmaxf(w1.z, w1.w)));
    m = fmaxf(m, fmaxf(fmaxf(w2.x, w2.y), fmaxf(w2.z, w2.w)));
    m = fmaxf(m, fmaxf(fmaxf(w3.x, w3.y), fmaxf(w3.z, w3.w)));
    #pragma unroll
    for (int off = 1; off < 64; off <<= 1) m = fmaxf(m, __shfl_xor(m, off, 64));

    float s = __expf(w0.x - m) + __expf(w0.y - m) + __expf(w0.z - m) + __expf(w0.w - m)
            + __expf(w1.x - m) + __expf(w1.y - m) + __expf(w1.z - m) + __expf(w1.w - m)
            + __expf(w2.x - m) + __expf(w2.y - m) + __expf(w2.z - m) + __expf(w2.w - m)
            + __expf(w3.x - m) + __expf(w3.y - m) + __expf(w3.z - m) + __expf(w3.w - m);
    #pragma unroll
    for (int off = 1; off < 64; off <<= 1) s += __shfl_xor(s, off, 64);

    const float lse = m + __logf(s);

    float pz = __expf(row[0] - lse);        // blank probability
    float px = 0.0f, py = 0.0f;             // 0 = additive identity: masks
    const int l0 = 2 * lane, l1i = 2 * lane + 1;
    if (l0  < L) px = __expf(row[tgt[b * L + l0 ]] - lse);  // row is L1-hot
    if (l1i < L) py = __expf(row[tgt[b * L + l1i]] - lse);

    float4 o; o.x = px; o.y = py; o.z = pz; o.w = 0.0f;
    gat[(size_t)wid * 64 + lane] = o;
}

// ---------------------------------------------------------------------------
// Kernel 2: CTC alpha, PRODUCER-CONSUMER LDS pipeline (block = 192 = 3 waves).
//   wave 0 (consumer): r4-verified math; per 16-step chunk: 16 ds_read_b128
//     from a barrier-published LDS buffer (compiler stages lgkmcnt well —
//     m97). Issues ZERO VMEM in the main loop, so any conservative
//     compiler vmcnt(0) before its ds_reads is free (per-wave counter = 0).
//   waves 1,2 (DMA prefetchers, alternating chunk parity): chunk q is
//     DMA-issued (16x global_load_lds) two segments early and vmcnt(0)-
//     drained one segment early — the drain stalls only the prefetcher,
//     OFF the critical path. Per-wave vmcnt isolation makes this exact.
// Budget: chunk has ~2 consumer windows (~800-1000cyc) >= ~900cyc HBM lat.
// Sync-count identical for all 3 waves (all derive nc from uniform il).
// Numerics bit-identical to r4 (same STEP/RENORM cadence) -> pass safe.
// Diagnostics: Workgroup_Size=192, LDS_Block_Size=49152.
// ---------------------------------------------------------------------------
__global__ __launch_bounds__(192, 1)
void ctc_alpha_wave(const float4* __restrict__ gat,
                    const int* __restrict__ tgt,
                    const int* __restrict__ in_len,
                    const int* __restrict__ tg_len,
                    float* __restrict__ out,
                    int T, int L, int B) {
    __shared__ float4 buf[3][16][64];       // 48 KiB, 3 chunk buffers

    const int b = blockIdx.x;
    const int w = threadIdx.x >> 6;         // 0 = consumer, 1/2 = prefetchers
    const int k = threadIdx.x & 63;
    const int S = 2 * L + 1;

    const int il = in_len[b];
    const int tl = tg_len[b];
    const float4* gb = gat + (size_t)b * T * 64;

    const int tmax = (il < T) ? il : T;
    const int nsteps = tmax - 1;            // steps t = 1 .. tmax-1
    const int nc = (nsteps >= 16) ? (nsteps >> 4) : 0;   // full 16-step chunks
    // chunk c rows: t = 1+16c .. 16+16c  (all <= nsteps <= T-1: never clamped)

    if (w > 0) {
        // ---- DMA prefetch waves; parity p handles chunks q with q%2==p ----
        const int p = w - 1;
#define ISSUE_CHUNK(q)                                                       \
        { const int t0 = 1 + 16 * (q);                                       \
          for (int j = 0; j < 16; ++j)                                       \
              gload_lds16(&gb[(size_t)(t0 + j) * 64 + k], &buf[(q) % 3][j][0]); }
        if (p < nc) ISSUE_CHUNK(p)           // prologue: chunks 0 and 1
        asm volatile("s_waitcnt vmcnt(0)" ::: "memory");
        __syncthreads();                     // S_{-1}: chunks 0,1 published
        for (int s = 0; s < nc; ++s) {
            if ((s & 1) == p) {
                if (s + 2 < nc) ISSUE_CHUNK(s + 2)   // issue 2 segments early
            } else {
                asm volatile("s_waitcnt vmcnt(0)" ::: "memory"); // drain s+1
            }
            __syncthreads();                 // S_s
        }
#undef ISSUE_CHUNK
        return;                              // no barriers after this point
    }

    // ---- consumer wave (round-4 verified math) ----
    const bool v1 = (4 * k + 1 < S);
    const bool v3 = (4 * k + 3 < S);
    bool sk1 = false, sk3 = false;
    if (v1 && k > 0) {
        int tc = tgt[b * L + 2 * k], tp = tgt[b * L + 2 * k - 1];
        sk1 = (tc != 0) && (tc != tp);
    }
    if (v3) {
        int tc = tgt[b * L + 2 * k + 1], tp = tgt[b * L + 2 * k];
        sk3 = (tc != 0) && (tc != tp);
    }

    // t = 0 init (probabilities)
    float q0 = 0.0f, q1 = 0.0f, q2 = 0.0f, q3 = 0.0f;
    {
        float4 f0 = gb[k];
        if (k == 0) { q0 = f0.z; q1 = (tl > 0) ? f0.x : 0.0f; }
    }
    int acc = 0;                            // running log2 scale (integer)

    int t = 1;

#define STEP(p)                                                              \
    {                                                                        \
        float qm = DPPF(q3, 0x138);          /* wave_shr:1 -> lane k-1 q3 */ \
        qm = (k == 0) ? 0.0f : qm;                                           \
        float n0 = (q0 + qm) * (p).z;                                        \
        float n1 = (q1 + q0 + (sk1 ? qm : 0.0f)) * (p).x;                    \
        float n2 = (q2 + q1) * (p).z;                                        \
        float n3 = (q3 + q2 + (sk3 ? q1 : 0.0f)) * (p).y;                    \
        q0 = n0; q1 = n1; q2 = n2; q3 = n3;                                  \
        ++t;                                                                 \
    }

// exact power-of-2 renorm: brings wave max's exponent to 0; no rounding.
#define RENORM                                                               \
    {                                                                        \
        float mx = fmaxf(fmaxf(q0, q1), fmaxf(q2, q3));                      \
        mx = fmaxf(mx, DPPF(mx, 0x111));     /* row_shr:1  */                \
        mx = fmaxf(mx, DPPF(mx, 0x112));     /* row_shr:2  */                \
        mx = fmaxf(mx, DPPF(mx, 0x114));     /* row_shr:4  */                \
        mx = fmaxf(mx, DPPF(mx, 0x118));     /* row_shr:8  */                \
        mx = fmaxf(mx, DPPF(mx, 0x142));     /* row_bcast:15 */              \
        mx = fmaxf(mx, DPPF(mx, 0x143));     /* row_bcast:31 */              \
        int me = (__builtin_amdgcn_readlane(__float_as_int(mx), 63) >> 23) & 0xff; \
        float sc = __int_as_float(((me == 0) ? 127 : (254 - me)) << 23);     \
        acc += (me == 0) ? 0 : (me - 127);                                   \
        q0 *= sc; q1 *= sc; q2 *= sc; q3 *= sc;                              \
    }

    __syncthreads();                         // S_{-1}: chunks 0,1 ready
    for (int c = 0; c < nc; ++c) {
        const float4* bc = &buf[c % 3][0][0];
        // 16 independent ds_read_b128 — compiler stages lgkmcnt (m97 pattern)
        float4 p0  = bc[ 0 * 64 + k], p1  = bc[ 1 * 64 + k];
        float4 p2  = bc[ 2 * 64 + k], p3  = bc[ 3 * 64 + k];
        float4 p4  = bc[ 4 * 64 + k], p5  = bc[ 5 * 64 + k];
        float4 p6  = bc[ 6 * 64 + k], p7  = bc[ 7 * 64 + k];
        float4 p8  = bc[ 8 * 64 + k], p9  = bc[ 9 * 64 + k];
        float4 p10 = bc[10 * 64 + k], p11 = bc[11 * 64 + k];
        float4 p12 = bc[12 * 64 + k], p13 = bc[13 * 64 + k];
        float4 p14 = bc[14 * 64 + k], p15 = bc[15 * 64 + k];
        STEP(p0)  STEP(p1)  STEP(p2)  STEP(p3)  RENORM
        STEP(p4)  STEP(p5)  STEP(p6)  STEP(p7)  RENORM
        STEP(p8)  STEP(p9)  STEP(p10) STEP(p11) RENORM
        STEP(p12) STEP(p13) STEP(p14) STEP(p15) RENORM
        __syncthreads();                     // S_c: publish next chunk
    }

    // tail (< 16 steps), verified round-4 direct-load path (cache-warm)
    while (t + 4 <= tmax) {
        { float4 pa = gb[(size_t)t * 64 + k]; STEP(pa) }
        { float4 pb = gb[(size_t)t * 64 + k]; STEP(pb) }
        { float4 pc = gb[(size_t)t * 64 + k]; STEP(pc) }
        { float4 pd = gb[(size_t)t * 64 + k]; STEP(pd) }
        RENORM
    }
    while (t < tmax) {
        float4 pr = gb[(size_t)t * 64 + k]; STEP(pr)
    }
#undef STEP
#undef RENORM

    // final = logaddexp(alpha[2*tl], alpha[2*tl-1]) at t = il-1
    const int e1 = 2 * tl;
    const int e2 = (2 * tl - 1 > 0) ? (2 * tl - 1) : 0;
    const int i1 = e1 & 3, l1 = e1 >> 2;
    const int i2 = e2 & 3, l2 = e2 >> 2;
    float m1 = (i1 == 0) ? q0 : (i1 == 1) ? q1 : (i1 == 2) ? q2 : q3;
    float m2 = (i2 == 0) ? q0 : (i2 == 1) ? q1 : (i2 == 2) ? q2 : q3;
    float ev1 = __shfl(m1, l1, 64);
    float ev2 = __shfl(m2, l2, 64);
    float qs = ev1 + ev2;

    if (k == 0) {
        float loss = 0.0f;
        if (qs > 0.0f && il >= 1 && il <= T) {
            float fin_log2 = (float)acc + log2f(qs);
            loss = -fin_log2 * 0.6931471805599453f;      // ln2
        }
        atomicAdd(out, loss / ((float)tl * (float)B));
    }
}

extern "C" void kernel_launch(void* const* d_in, const int* in_sizes, int n_in,
                              void* d_out, int out_size, void* d_ws, size_t ws_size,
                              hipStream_t stream) {
    const float* pred = (const float*)d_in[0];
    const int*   plen = (const int*)d_in[1];
    const int*   gt   = (const int*)d_in[2];
    const int*   glen = (const int*)d_in[3];
    float* out = (float*)d_out;

    const int B = in_sizes[1];
    const int L = in_sizes[2] / B;
    const int V = 1024;                      // problem-fixed (reference setup)
    const int T = in_sizes[0] / B / V;

    float4* gat = (float4*)d_ws;             // B*T*64 float4 = ~32.8 MiB

    const int nrows = B * T;                 // one wave per row
    const int wavesPerBlk = 4;               // block = 256
    const int nblk = (nrows + wavesPerBlk - 1) / wavesPerBlk;
    lse_gather_kernel<<<nblk, 64 * wavesPerBlk, 0, stream>>>(
        pred, gt, gat, out, T, V, L, nrows);

    ctc_alpha_wave<<<B, 192, 0, stream>>>(gat, gt, plen, glen, out, T, L, B);
}